// Round 3
// baseline (43.244 us; speedup 1.0000x reference)
//
#include <hip/hip_runtime.h>
#include <math.h>

// Sliding-window (n=64) temperature-softmax attention, fp32, N=4194304.
// Segmented two-sided online-softmax scan, SEG=16, one thread per segment.
// ROUND 3 = MEASUREMENT ROUND: identical kernel launched 3x (launch 1 -> d_out,
// launches 2,3 -> d_ws) to split fixed replay overhead from true kernel time:
//   dur3 - dur1 = 2 * k_warm.

#define SEG 16

__device__ __forceinline__ float fexp2(float x) { return __builtin_amdgcn_exp2f(x); }

__global__ __launch_bounds__(256, 3) void soft_attn_kernel(
    const float* __restrict__ x, const float* __restrict__ w_tau,
    float* __restrict__ out)
{
    const int s = blockIdx.x * blockDim.x + threadIdx.x;
    const float tau = log1pf(expf(w_tau[0])) + 1e-5f;
    const float C = 1.4426950408889634f / tau;   // log2(e)/tau

    // Emission segment values (segment s always exists).
    float ve[SEG];
    {
        const float4* p4 = reinterpret_cast<const float4*>(x + (size_t)s * SEG);
#pragma unroll
        for (int k = 0; k < SEG / 4; ++k) {
            float4 t = p4[k];
            ve[4*k] = t.x; ve[4*k+1] = t.y; ve[4*k+2] = t.z; ve[4*k+3] = t.w;
        }
    }

    float Sm[SEG], Sa[SEG], Sb[SEG];          // suffix triples of seg s-4, idx p = start p+1
    float m = -INFINITY, r0 = 0.f, r1 = 0.f;  // running prefix triple

    if (s >= 4) {
        float v0[SEG], v1[3 * SEG];
        {
            const float4* p4 = reinterpret_cast<const float4*>(x + (size_t)(s - 4) * SEG);
#pragma unroll
            for (int k = 0; k < SEG / 4; ++k) {
                float4 t = p4[k];
                v0[4*k] = t.x; v0[4*k+1] = t.y; v0[4*k+2] = t.z; v0[4*k+3] = t.w;
            }
        }
        {
            const float4* p4 = reinterpret_cast<const float4*>(x + (size_t)(s - 3) * SEG);
#pragma unroll
            for (int k = 0; k < 3 * SEG / 4; ++k) {
                float4 t = p4[k];
                v1[4*k] = t.x; v1[4*k+1] = t.y; v1[4*k+2] = t.z; v1[4*k+3] = t.w;
            }
        }
        float sm = -INFINITY, sa = 0.f, sb = 0.f;
#pragma unroll
        for (int q = SEG - 1; q >= 1; --q) {
            const float val = v0[q];
            const float nm = fmaxf(sm, val);
            const float e  = fexp2(-fabsf(sm - val) * C);
            const float ea = (val >= sm) ? 1.f : e;
            const float eb = (val >= sm) ? e : 1.f;
            sa = sa * eb + ea;
            sb = sb * eb + val * ea;
            sm = nm;
            Sm[q-1] = sm; Sa[q-1] = sa; Sb[q-1] = sb;
        }
        Sm[SEG-1] = -INFINITY; Sa[SEG-1] = 0.f; Sb[SEG-1] = 0.f;
#pragma unroll
        for (int q = 0; q < 3 * SEG; ++q) {
            const float val = v1[q];
            const float nm = fmaxf(m, val);
            const float e  = fexp2(-fabsf(m - val) * C);
            const float ea = (val >= m) ? 1.f : e;
            const float eb = (val >= m) ? e : 1.f;
            r0 = r0 * eb + ea;
            r1 = r1 * eb + val * ea;
            m = nm;
        }
    } else {
#pragma unroll
        for (int q = 0; q < SEG; ++q) { Sm[q] = -INFINITY; Sa[q] = 0.f; Sb[q] = 0.f; }
        for (int j = 0; j < 3; ++j) {
            const int t = s - 3 + j;
            if (t >= 0) {
                const float* p = x + (size_t)t * SEG;
                for (int q = 0; q < SEG; ++q) {
                    const float val = p[q];
                    const float nm = fmaxf(m, val);
                    const float e  = fexp2(-fabsf(m - val) * C);
                    const float ea = (val >= m) ? 1.f : e;
                    const float eb = (val >= m) ? e : 1.f;
                    r0 = r0 * eb + ea;
                    r1 = r1 * eb + val * ea;
                    m = nm;
                }
            }
        }
    }

    float4* o4 = reinterpret_cast<float4*>(out + (size_t)s * SEG);
    float4 ob;
#pragma unroll
    for (int p = 0; p < SEG; ++p) {
        const float val = ve[p];
        const float nm = fmaxf(m, val);
        const float e  = fexp2(-fabsf(m - val) * C);
        const float ea = (val >= m) ? 1.f : e;
        const float eb = (val >= m) ? e : 1.f;
        r0 = r0 * eb + ea;
        r1 = r1 * eb + val * ea;
        m = nm;
        const float smv = Sm[p];
        const float ec  = fexp2(-fabsf(m - smv) * C);
        const float e1  = (m >= smv) ? 1.f : ec;
        const float e2  = (m >= smv) ? ec : 1.f;
        const float t0  = r0 * e1 + Sa[p] * e2;
        const float t1  = r1 * e1 + Sb[p] * e2;
        const float res = t1 * __builtin_amdgcn_rcpf(t0);
        if      ((p & 3) == 0) ob.x = res;
        else if ((p & 3) == 1) ob.y = res;
        else if ((p & 3) == 2) ob.z = res;
        else { ob.w = res; o4[p >> 2] = ob; }
    }
}

extern "C" void kernel_launch(void* const* d_in, const int* in_sizes, int n_in,
                              void* d_out, int out_size, void* d_ws, size_t ws_size,
                              hipStream_t stream) {
    const float* x = (const float*)d_in[0];
    const float* w = (const float*)d_in[1];
    float* outp = (float*)d_out;
    const int N = in_sizes[0];                 // 4194304, divisible by SEG
    const int nseg = N / SEG;                  // 262144
    const int threads = 256;
    const int blocks = (nseg + threads - 1) / threads;   // 1024

    // Launch 1: real output.
    soft_attn_kernel<<<blocks, threads, 0, stream>>>(x, w, outp);

    // Launches 2,3: identical work into scratch (deterministic; d_out untouched).
    // Purpose: dur3 - dur1 = 2*k_warm -> separates fixed replay overhead from
    // true kernel cost, since our dispatch row is hidden below the poison fills.
    float* scratch = (ws_size >= (size_t)N * sizeof(float)) ? (float*)d_ws : outp;
    soft_attn_kernel<<<blocks, threads, 0, stream>>>(x, w, scratch);
    soft_attn_kernel<<<blocks, threads, 0, stream>>>(x, w, scratch);
}

// Round 4
// 18.147 us; speedup vs baseline: 2.3830x; 2.3830x over previous
//
#include <hip/hip_runtime.h>
#include <math.h>

// Sliding-window (n=64) temperature-softmax attention, fp32, N=4194304.
// Segmented two-sided online-softmax scan, SEG=16, one thread per segment.
// Round 4: LDS staging. Block stages 260 segments (256 + 4 halo) coalesced,
// threads stream from LDS (padded rows, stride 20 floats -> conflict-free
// minimum-phase ds_read_b128). Kills the 64-lines-per-instruction strided
// global loads that round-3 measurement identified as the bottleneck.

#define SEG 16
#define BLK 256
#define HALO 4
#define ROWS (BLK + HALO)      // 260
#define RSTRIDE 20             // floats per LDS row (16 data + 4 pad)

__device__ __forceinline__ float fexp2(float x) { return __builtin_amdgcn_exp2f(x); }

__global__ __launch_bounds__(256, 4) void soft_attn_kernel(
    const float* __restrict__ x, const float* __restrict__ w_tau,
    float* __restrict__ out)
{
    __shared__ float lds[ROWS * RSTRIDE];   // 20800 B

    const int tid = threadIdx.x;
    const int S0  = blockIdx.x * BLK;       // first segment of this block
    const int s   = S0 + tid;               // this thread's segment

    const float tau = log1pf(expf(w_tau[0])) + 1e-5f;
    const float C = 1.4426950408889634f / tau;   // log2(e)/tau

    // ---- Stage [S0-4, S0+256) segments into LDS, coalesced ----
    {
        const int base4 = (S0 - HALO) * (SEG / 4);    // float4 index of region start
#pragma unroll
        for (int it = 0; it < 5; ++it) {
            const int i = tid + it * BLK;             // 0..1039 (+pad)
            if (i < ROWS * 4) {
                const int g4 = base4 + i;
                if (g4 >= 0) {                        // only block 0 has negative halo
                    const float4 t = reinterpret_cast<const float4*>(x)[g4];
                    const int r = i >> 2, c = i & 3;
                    *reinterpret_cast<float4*>(&lds[r * RSTRIDE + c * 4]) = t;
                }
            }
        }
    }
    __syncthreads();

    // scan-step macro: online-softmax monoid append, one exp2 per element
#define STEP(val, M, R0, R1)                                   \
    {                                                          \
        const float _v = (val);                                \
        const float _e = fexp2(-fabsf((M) - _v) * C);          \
        const float _ea = (_v >= (M)) ? 1.f : _e;              \
        const float _eb = (_v >= (M)) ? _e : 1.f;              \
        (R0) = (R0) * _eb + _ea;                               \
        (R1) = (R1) * _eb + _v * _ea;                          \
        (M) = fmaxf((M), _v);                                  \
    }

    float Sm[SEG], Sa[SEG], Sb[SEG];          // suffix triples of seg s-4
    float m = -INFINITY, r0 = 0.f, r1 = 0.f;  // running prefix triple

    const bool fast = (blockIdx.x != 0) || (tid >= HALO);
    if (fast) {
        // Suffix scan over seg s-4 (LDS row tid), q = 15..1, store triple at q-1.
        const float* row0 = &lds[tid * RSTRIDE];
        float v0[SEG];
#pragma unroll
        for (int c = 0; c < 4; ++c) {
            const float4 t = *reinterpret_cast<const float4*>(row0 + 4 * c);
            v0[4*c] = t.x; v0[4*c+1] = t.y; v0[4*c+2] = t.z; v0[4*c+3] = t.w;
        }
        float sm = -INFINITY, sa = 0.f, sb = 0.f;
        Sm[SEG-1] = -INFINITY; Sa[SEG-1] = 0.f; Sb[SEG-1] = 0.f;
#pragma unroll
        for (int q = SEG - 1; q >= 1; --q) {
            STEP(v0[q], sm, sa, sb);
            Sm[q-1] = sm; Sa[q-1] = sa; Sb[q-1] = sb;
        }
        // Prefix scan over segs s-3..s-1 (LDS rows tid+1..tid+3), streamed.
#pragma unroll
        for (int r = 1; r <= 3; ++r) {
            const float* row = &lds[(tid + r) * RSTRIDE];
#pragma unroll
            for (int c = 0; c < 4; ++c) {
                const float4 t = *reinterpret_cast<const float4*>(row + 4 * c);
                STEP(t.x, m, r0, r1); STEP(t.y, m, r0, r1);
                STEP(t.z, m, r0, r1); STEP(t.w, m, r0, r1);
            }
        }
    } else {
        // Threads s = 0..3 only: empty suffix, guarded global prefix.
#pragma unroll
        for (int q = 0; q < SEG; ++q) { Sm[q] = -INFINITY; Sa[q] = 0.f; Sb[q] = 0.f; }
        for (int t = s - 3; t < s; ++t) {
            if (t >= 0) {
                const float* p = x + (size_t)t * SEG;
                for (int q = 0; q < SEG; ++q) STEP(p[q], m, r0, r1);
            }
        }
    }

    // Emission over seg s (LDS row tid+4): continue prefix, combine with suffix.
    const float* rowe = &lds[(tid + HALO) * RSTRIDE];
    float4* o4 = reinterpret_cast<float4*>(out + (size_t)s * SEG);
#pragma unroll
    for (int c = 0; c < 4; ++c) {
        const float4 t = *reinterpret_cast<const float4*>(rowe + 4 * c);
        float4 ob;
#pragma unroll
        for (int j = 0; j < 4; ++j) {
            const int p = 4 * c + j;
            const float val = (j == 0) ? t.x : (j == 1) ? t.y : (j == 2) ? t.z : t.w;
            STEP(val, m, r0, r1);
            const float smv = Sm[p];
            const float ec  = fexp2(-fabsf(m - smv) * C);
            const float e1  = (m >= smv) ? 1.f : ec;
            const float e2  = (m >= smv) ? ec : 1.f;
            const float t0  = r0 * e1 + Sa[p] * e2;
            const float t1  = r1 * e1 + Sb[p] * e2;
            const float res = t1 * __builtin_amdgcn_rcpf(t0);  // t0 in [1,64]
            if      (j == 0) ob.x = res;
            else if (j == 1) ob.y = res;
            else if (j == 2) ob.z = res;
            else             ob.w = res;
        }
        o4[c] = ob;
    }
#undef STEP
}

extern "C" void kernel_launch(void* const* d_in, const int* in_sizes, int n_in,
                              void* d_out, int out_size, void* d_ws, size_t ws_size,
                              hipStream_t stream) {
    const float* x = (const float*)d_in[0];
    const float* w = (const float*)d_in[1];
    float* outp = (float*)d_out;
    const int N = in_sizes[0];                 // 4194304
    const int nseg = N / SEG;                  // 262144
    const int blocks = nseg / BLK;             // 1024
    soft_attn_kernel<<<blocks, BLK, 0, stream>>>(x, w, outp);
}